// Round 5
// baseline (808.321 us; speedup 1.0000x reference)
//
#include <hip/hip_runtime.h>

typedef __bf16 bf16_t;
typedef bf16_t bf16x8 __attribute__((ext_vector_type(8)));
typedef float f32x4 __attribute__((ext_vector_type(4)));

#define BATCH 16384
#define HID 256

// ---------- bf16 helpers (manual RNE, no header dependency) ----------
__device__ __forceinline__ ushort f2b(float f) {
  union { float f; unsigned u; } v; v.f = f;
  unsigned u = v.u;
  unsigned r = (u + 0x7fffu + ((u >> 16) & 1u)) >> 16;
  return (ushort)r;
}
__device__ __forceinline__ float b2f(ushort u) {
  union { unsigned u; float f; } v; v.u = ((unsigned)u) << 16; return v.f;
}
__device__ __forceinline__ void loadbf4(const ushort* __restrict__ p, float* o) {
  uint2 q = *(const uint2*)p;
  o[0] = b2f((ushort)(q.x & 0xffffu));
  o[1] = b2f((ushort)(q.x >> 16));
  o[2] = b2f((ushort)(q.y & 0xffffu));
  o[3] = b2f((ushort)(q.y >> 16));
}
__device__ __forceinline__ uint2 packbf4(const float* v) {
  uint2 q;
  q.x = (unsigned)f2b(v[0]) | ((unsigned)f2b(v[1]) << 16);
  q.y = (unsigned)f2b(v[2]) | ((unsigned)f2b(v[3]) << 16);
  return q;
}

// ---------- convert fp32 -> bf16 (x and h in one launch) ----------
__global__ __launch_bounds__(256)
void f2b2_kernel(const float* __restrict__ a, const float* __restrict__ b,
                 ushort* __restrict__ oa, ushort* __restrict__ ob) {
  int bid = blockIdx.x;
  const float* in = (bid < 4096) ? a : b;
  ushort* out     = (bid < 4096) ? oa : ob;
  int t = (bid & 4095) * 256 + threadIdx.x;
  float4 v = *(const float4*)(in + (size_t)t * 4);
  float q[4] = {v.x, v.y, v.z, v.w};
  *(uint2*)(out + (size_t)t * 4) = packbf4(q);
}

// ---------- build transposed bf16 weights: Wt[ksel*256+d][h] = W[ksel][h][d] ----------
__global__ __launch_bounds__(256)
void wt2_kernel(const float* __restrict__ L, const float* __restrict__ R,
                ushort* __restrict__ Lt, ushort* __restrict__ Rt) {
  int bid = blockIdx.x;
  const float* W = (bid < 1024) ? L : R;
  ushort* Wt     = (bid < 1024) ? Lt : Rt;
  int idx = (bid & 1023) * 256 + threadIdx.x;
  int c = idx >> 8, hh = idx & 255;
  int ks = c >> 8, d = c & 255;
  Wt[idx] = f2b(W[ks * 65536 + hh * 256 + d]);
}

// ---------- B-resident persistent GEMM: P[M,N] = A[M,256] @ Wt ----------
// 512 threads (8 waves, 4M x 2N), 256x128 output tile. Grid = 256 = 1 block/CU.
// LDS: Bres = full K=256 B-strip (64 KB, loaded ONCE per job) + A dbuf 2x32 KB = 128 KB.
// Per K-step only A is staged (4 global_load_lds / wave); VMW(4) mid-tile, VMW(0) at tile end.
// Block mapping: strip = bid/SPB, w = bid%SPB, M-tiles m = w + k*SPB  (SPB multiple of 8
// => blocks sharing an A-panel have equal bid%8 => same XCD => A panel L2-resident).
// Epilogues: 0 = raw bf16 store; 1 = sigmoid-fuse (reads xL P-matrix, writes gnode/z1b/rb).
struct GJob {
  const ushort* A; const ushort* B; ushort* out;
  const ushort* Padd;   // epi1: xL P-matrix (row stride 1024)
  const float* bias;    // epi1
  float* gnode; ushort* z1b; ushort* rb;   // epi1
  int nstrip;   // 8 (N=1024) or 4 (N=512)
  int epi;      // 0 raw, 1 sigmoid
};

__global__ __launch_bounds__(512, 2)
void fgemm_kernel(GJob j0, GJob j1, GJob j2, int njobs) {
  __shared__ __align__(16) ushort As[2][256 * 64];    // 2 x 32 KB A double-buffer
  __shared__ __align__(16) ushort Bres[4][128 * 64];  // 4 x 16 KB: all of K resident

  const int bid  = blockIdx.x;
  const int tid  = threadIdx.x;
  const int lane = tid & 63;
  const int wave = tid >> 6;                // 0..7
  const int wm   = (wave >> 1) * 64;        // 0,64,128,192
  const int wn   = (wave & 1) * 64;         // 0,64
  const int row  = lane & 15;
  const int quad = lane >> 4;
  const int r_s  = lane >> 3;               // row within 8-row chunk
  const int g_s  = lane & 7;                // 16B granule within row
  const int gsw  = g_s ^ r_s;               // inverse-swizzled source granule

#define VMW(n) asm volatile("s_waitcnt vmcnt(" #n ")" ::: "memory")

#define STAGE_A(buf, mb, kt)                                                        \
  {                                                                                 \
    const int bufs = (buf);                                                         \
    const size_t mbs = (mb);                                                        \
    const int k0s = (kt) * 64;                                                      \
    for (int i_s = 0; i_s < 4; ++i_s) {                                             \
      const int cis = wave * 4 + i_s;                                               \
      __builtin_amdgcn_global_load_lds(                                             \
        (const __attribute__((address_space(1))) void*)(j.A + (mbs + cis * 8 + r_s) * 256 + k0s + gsw * 8), \
        (__attribute__((address_space(3))) void*)&As[bufs][cis * 512], 16, 0, 0);   \
    }                                                                               \
  }

#define COMPUTE(buf, kt)                                                            \
  {                                                                                 \
    const int bufc = (buf);                                                         \
    const int ktc  = (kt);                                                          \
    bf16x8 af[2][4], bfr[2][4];                                                     \
    for (int kkc = 0; kkc < 2; ++kkc)                                               \
      for (int frc = 0; frc < 4; ++frc) {                                           \
        const int ar = wm + frc * 16 + row;                                         \
        af[kkc][frc] = *(const bf16x8*)&As[bufc][ar * 64 + ((kkc * 4 + quad) ^ (ar & 7)) * 8]; \
        const int br = wn + frc * 16 + row;                                         \
        bfr[kkc][frc] = *(const bf16x8*)&Bres[ktc][br * 64 + ((kkc * 4 + quad) ^ (br & 7)) * 8]; \
      }                                                                             \
    __builtin_amdgcn_s_setprio(1);                                                  \
    for (int kkc = 0; kkc < 2; ++kkc)                                               \
      for (int ti = 0; ti < 4; ++ti)                                                \
        for (int tj = 0; tj < 4; ++tj)                                              \
          acc[ti][tj] = __builtin_amdgcn_mfma_f32_16x16x32_bf16(                    \
              af[kkc][ti], bfr[kkc][tj], acc[ti][tj], 0, 0, 0);                     \
    __builtin_amdgcn_s_setprio(0);                                                  \
  }

  for (int ji = 0; ji < njobs; ++ji) {
    const GJob j = (ji == 0) ? j0 : (ji == 1) ? j1 : j2;
    const int SPB   = 256 / j.nstrip;       // 32 (N=1024) or 64 (N=512)
    const int T     = j.nstrip >> 2;        // M-tiles per block: 2 or 1
    const int strip = bid / SPB;
    const int w     = bid % SPB;
    const int bn    = strip * 128;
    const int N     = j.nstrip * 128;

    __builtin_amdgcn_s_barrier();           // prior job's Bres reads done
    // stage B resident: 64 chunks of 1 KB, 8 per wave
    for (int c = 0; c < 8; ++c) {
      const int gc = wave * 8 + c, ktb = gc >> 4, cib = gc & 15;
      __builtin_amdgcn_global_load_lds(
        (const __attribute__((address_space(1))) void*)(j.B + (size_t)(bn + cib * 8 + r_s) * 256 + ktb * 64 + gsw * 8),
        (__attribute__((address_space(3))) void*)&Bres[ktb][cib * 512], 16, 0, 0);
    }

    for (int k = 0; k < T; ++k) {
      const size_t mbase = (size_t)(w + k * SPB) * 256;
      f32x4 acc[4][4] = {};
      STAGE_A(0, mbase, 0);
#pragma unroll
      for (int kt = 0; kt < 4; ++kt) {
        __builtin_amdgcn_s_barrier();       // WAR: A-buffer about to be overwritten is free
        if (kt < 3) { STAGE_A((kt + 1) & 1, mbase, kt + 1); VMW(4); }
        else        { VMW(0); }
        __builtin_amdgcn_s_barrier();       // stage-kt data (and Bres on first pass) landed
        __builtin_amdgcn_sched_barrier(0);  // pin ds_reads behind the wait
        COMPUTE(kt & 1, kt);
      }
      if (j.epi == 0) {
        for (int ti = 0; ti < 4; ++ti)
          for (int tj = 0; tj < 4; ++tj)
            for (int r2 = 0; r2 < 4; ++r2) {
              const size_t gm = mbase + wm + ti * 16 + quad * 4 + r2;
              const int    gn = bn + wn + tj * 16 + row;
              j.out[gm * N + gn] = f2b(acc[ti][tj][r2]);
            }
      } else {
        for (int ti = 0; ti < 4; ++ti)
          for (int tj = 0; tj < 4; ++tj)
            for (int r2 = 0; r2 < 4; ++r2) {
              const size_t gm = mbase + wm + ti * 16 + quad * 4 + r2;
              const int    gn = bn + wn + tj * 16 + row;
              const float p0 = b2f(j.Padd[gm * 1024 + gn]);
              const float s  = 1.0f / (1.0f + expf(-(acc[ti][tj][r2] + p0 + j.bias[gn])));
              const size_t g = gm * 2304;
              if (gn < 256) {
                j.gnode[g + gn] = s;          // slot 0 (z1)
                j.gnode[g + 512 + gn] = s;    // slot 2 (z2 == z1)
                j.z1b[gm * 256 + gn] = f2b(s);
              } else {
                const int d = gn - 256;
                j.gnode[g + 256 + d] = s;     // slot 1 (r)
                j.rb[gm * 256 + d] = f2b(s);
              }
            }
      }
    }
  }
#undef STAGE_A
#undef COMPUTE
#undef VMW
}

// ---------- mixture: cand = f(P1,P2)+b ; softmax over k ; out ; score partials ----------
// mode 0: P1+P2+b   mode 1: 1-(P1+b)   mode 2: P1*P2+b
struct MixJob {
  const ushort* P1; const ushort* P2;
  float* gnode; ushort* act; float* hnext; float* part;
  int mode;
};

__global__ __launch_bounds__(256)
void mixN_kernel(MixJob j0, MixJob j1, MixJob j2, const float* __restrict__ bias,
                 const float* __restrict__ Ws) {
  const int jb = blockIdx.x >> 12;
  const MixJob j = (jb == 0) ? j0 : (jb == 1) ? j1 : j2;
  const int lb = blockIdx.x & 4095;

  const int tid  = threadIdx.x;
  const int wave = tid >> 6;
  const int lane = tid & 63;
  const int row  = lb * 4 + wave;
  const int d0   = lane * 4;
  float c[4][4];
  float sp[4];
  float4 w4 = *(const float4*)(Ws + d0);
  float ws4[4] = {w4.x, w4.y, w4.z, w4.w};
  for (int k = 0; k < 4; ++k) {
    float p1[4];
    loadbf4(j.P1 + (size_t)row * 1024 + k * 256 + d0, p1);
    float4 bb = *(const float4*)(bias + k * 256 + d0);
    float bv[4] = {bb.x, bb.y, bb.z, bb.w};
    float v[4];
    if (j.mode == 0) {
      float p2[4];
      loadbf4(j.P2 + (size_t)row * 1024 + k * 256 + d0, p2);
      for (int i = 0; i < 4; ++i) v[i] = p1[i] + p2[i] + bv[i];
    } else if (j.mode == 1) {
      for (int i = 0; i < 4; ++i) v[i] = 1.0f - (p1[i] + bv[i]);
    } else {
      float p2[4];
      loadbf4(j.P2 + (size_t)row * 1024 + k * 256 + d0, p2);
      for (int i = 0; i < 4; ++i) v[i] = p1[i] * p2[i] + bv[i];
    }
    float s = 0.f;
    for (int i = 0; i < 4; ++i) { c[k][i] = v[i]; s += v[i] * ws4[i]; }
    sp[k] = s;
  }
  for (int m = 1; m < 64; m <<= 1)
    for (int k = 0; k < 4; ++k) sp[k] += __shfl_xor(sp[k], m, 64);
  float mx = fmaxf(fmaxf(sp[0], sp[1]), fmaxf(sp[2], sp[3]));
  float e0 = expf(sp[0] - mx), e1 = expf(sp[1] - mx), e2 = expf(sp[2] - mx), e3 = expf(sp[3] - mx);
  float inv = 1.0f / (e0 + e1 + e2 + e3);
  float w0 = e0 * inv, w1 = e1 * inv, w2 = e2 * inv, w3 = e3 * inv;
  float o[4];
  for (int i = 0; i < 4; ++i) o[i] = w0 * c[0][i] + w1 * c[1][i] + w2 * c[2][i] + w3 * c[3][i];
  size_t g = (size_t)row * 2304 + d0;
  for (int i = 0; i < 4; ++i) j.gnode[g + i] = o[i];
  if (j.act) *(uint2*)(j.act + (size_t)row * 256 + d0) = packbf4(o);
  if (j.hnext) { float4 ov = {o[0], o[1], o[2], o[3]}; *(float4*)(j.hnext + (size_t)row * 256 + d0) = ov; }
  __shared__ float sred[4][4];
  if (lane == 0) for (int k = 0; k < 4; ++k) sred[wave][k] = sp[k];
  __syncthreads();
  if (tid < 4)
    j.part[lb * 4 + tid] = sred[0][tid] + sred[1][tid] + sred[2][tid] + sred[3][tid];
}

// ---------- finalize: reduce score partials, argmax + margin, G_structure ----------
__global__ __launch_bounds__(256)
void fin_kernel(const float* __restrict__ part, float* __restrict__ gs,
                float* __restrict__ margins) {
  __shared__ float red[256][4];
  __shared__ float sfin[6][4];
  int tid = threadIdx.x;
  for (int si = 0; si < 6; ++si) {
    float a[4] = {0.f, 0.f, 0.f, 0.f};
    for (int i = 0; i < 16; ++i) {
      const float* p = part + ((size_t)si * 4096 + tid + 256 * i) * 4;
      for (int k = 0; k < 4; ++k) a[k] += p[k];
    }
    for (int k = 0; k < 4; ++k) red[tid][k] = a[k];
    __syncthreads();
    for (int st = 128; st >= 1; st >>= 1) {
      if (tid < st) for (int k = 0; k < 4; ++k) red[tid][k] += red[tid + st][k];
      __syncthreads();
    }
    if (tid == 0) for (int k = 0; k < 4; ++k) sfin[si][k] = red[0][k];
    __syncthreads();
  }
  if (tid == 0) {
    gs[0] = 0.f; gs[1] = 1.f; gs[2] = 0.f;
    for (int si = 0; si < 6; ++si) {
      float s[4] = {sfin[si][0], sfin[si][1], sfin[si][2], sfin[si][3]};
      int idx = 0; float best = s[0];
      for (int k = 1; k < 4; ++k) if (s[k] > best) { best = s[k]; idx = k; }
      float second = -3.4e38f;
      for (int k = 0; k < 4; ++k) if (k != idx) second = fmaxf(second, s[k]);
      gs[3 + si] = (float)idx;
      margins[si] = best - second;
    }
  }
}

extern "C" void kernel_launch(void* const* d_in, const int* in_sizes, int n_in,
                              void* d_out, int out_size, void* d_ws, size_t ws_size,
                              hipStream_t stream) {
  const float* x    = (const float*)d_in[0];
  const float* h    = (const float*)d_in[1];
  const float* L    = (const float*)d_in[2];
  const float* R    = (const float*)d_in[3];
  const float* bias = (const float*)d_in[4];
  const float* Ws   = (const float*)d_in[5];

  float* out        = (float*)d_out;
  float* out_hnext  = out;                          // 4,194,304
  float* out_gs     = out + 4194304;                // 9
  float* out_gnode  = out + 4194313;                // 16384*9*256
  float* out_marg   = out + 41943049;               // 6

  // workspace layout (bf16 as ushort): 4 P-buffers + activations
  ushort* P0   = (ushort*)d_ws;                     // B*1024 each
  ushort* P1   = P0 + (size_t)BATCH * 1024;
  ushort* P2   = P1 + (size_t)BATCH * 1024;
  ushort* P3   = P2 + (size_t)BATCH * 1024;
  ushort* x2b  = P3 + (size_t)BATCH * 1024;
  ushort* h2b  = x2b + (size_t)BATCH * HID;
  ushort* z1b  = h2b + (size_t)BATCH * HID;
  ushort* rb   = z1b + (size_t)BATCH * HID;
  ushort* rhb  = rb  + (size_t)BATCH * HID;
  ushort* htb  = rhb + (size_t)BATCH * HID;
  ushort* omzb = htb + (size_t)BATCH * HID;
  ushort* ztb  = omzb + (size_t)BATCH * HID;
  ushort* z2hb = ztb + (size_t)BATCH * HID;
  ushort* Lt   = z2hb + (size_t)BATCH * HID;        // 1024*256
  ushort* Rt   = Lt + 1024 * 256;
  float*  part = (float*)(Rt + 1024 * 256);         // 6*16384 floats

  f2b2_kernel<<<8192, 256, 0, stream>>>(x, h, x2b, h2b);
  wt2_kernel<<<2048, 256, 0, stream>>>(L, R, Lt, Rt);

  GJob jz = {};

  // G1: xL -> P0 ; hL -> P1
  {
    GJob a = {x2b, Lt, P0, nullptr, nullptr, nullptr, nullptr, nullptr, 8, 0};
    GJob b = {h2b, Lt, P1, nullptr, nullptr, nullptr, nullptr, nullptr, 8, 0};
    fgemm_kernel<<<256, 512, 0, stream>>>(a, b, jz, 2);
  }
  // G2: sig = sigmoid(h@R[0:2] + xL[0:2] + b)  -> gnode slots 0,1,2 + z1b, rb
  {
    GJob a = {h2b, Rt, nullptr, P0, bias, out_gnode, z1b, rb, 4, 1};
    fgemm_kernel<<<256, 512, 0, stream>>>(a, jz, jz, 1);
  }
  // G3: rR -> P2 ; z1R -> P3
  {
    GJob a = {rb,  Rt, P2, nullptr, nullptr, nullptr, nullptr, nullptr, 8, 0};
    GJob b = {z1b, Rt, P3, nullptr, nullptr, nullptr, nullptr, nullptr, 8, 0};
    fgemm_kernel<<<256, 512, 0, stream>>>(a, b, jz, 2);
  }
  // M1: rh = sm(hL+rR+b) ; omz = sm(1-(z1R+b)) ; z2h = sm(hL*z1R+b)
  {
    MixJob m0 = {P1, P2, out_gnode + 3 * 256, rhb,  nullptr, part + 0 * 16384, 0};
    MixJob m1 = {P3, P3, out_gnode + 5 * 256, omzb, nullptr, part + 2 * 16384, 1};
    MixJob m2 = {P1, P3, out_gnode + 7 * 256, z2hb, nullptr, part + 4 * 16384, 2};
    mixN_kernel<<<12288, 256, 0, stream>>>(m0, m1, m2, bias, Ws);
  }
  // G4: rhR -> P1 ; omzR -> P2 ; z2hR -> P3
  {
    GJob a = {rhb,  Rt, P1, nullptr, nullptr, nullptr, nullptr, nullptr, 8, 0};
    GJob b = {omzb, Rt, P2, nullptr, nullptr, nullptr, nullptr, nullptr, 8, 0};
    GJob c = {z2hb, Rt, P3, nullptr, nullptr, nullptr, nullptr, nullptr, 8, 0};
    fgemm_kernel<<<256, 512, 0, stream>>>(a, b, c, 3);
  }
  // M2: ht = sm(xL + rhR + b)
  {
    MixJob m0 = {P0, P1, out_gnode + 4 * 256, htb, nullptr, part + 1 * 16384, 0};
    mixN_kernel<<<4096, 256, 0, stream>>>(m0, m0, m0, bias, Ws);
  }
  // G5: htL -> P0 (xL dead)
  {
    GJob a = {htb, Lt, P0, nullptr, nullptr, nullptr, nullptr, nullptr, 8, 0};
    fgemm_kernel<<<256, 512, 0, stream>>>(a, jz, jz, 1);
  }
  // M3: zt = sm(htL * omzR + b)
  {
    MixJob m0 = {P0, P2, out_gnode + 6 * 256, ztb, nullptr, part + 3 * 16384, 2};
    mixN_kernel<<<4096, 256, 0, stream>>>(m0, m0, m0, bias, Ws);
  }
  // G6: ztL -> P1 (rhR dead)
  {
    GJob a = {ztb, Lt, P1, nullptr, nullptr, nullptr, nullptr, nullptr, 8, 0};
    fgemm_kernel<<<256, 512, 0, stream>>>(a, jz, jz, 1);
  }
  // M4: hn = sm(ztL + z2hR + b) -> gnode8 + hnext(f32)
  {
    MixJob m0 = {P1, P3, out_gnode + 8 * 256, nullptr, out_hnext, part + 5 * 16384, 0};
    mixN_kernel<<<4096, 256, 0, stream>>>(m0, m0, m0, bias, Ws);
  }
  fin_kernel<<<1, 256, 0, stream>>>(part, out_gs, out_marg);
}

// Round 6
// 456.378 us; speedup vs baseline: 1.7712x; 1.7712x over previous
//
#include <hip/hip_runtime.h>

typedef __bf16 bf16_t;
typedef bf16_t bf16x8 __attribute__((ext_vector_type(8)));
typedef float f32x4 __attribute__((ext_vector_type(4)));

#define BATCH 16384
#define HID 256

// ---------- bf16 helpers (manual RNE, no header dependency) ----------
__device__ __forceinline__ ushort f2b(float f) {
  union { float f; unsigned u; } v; v.f = f;
  unsigned u = v.u;
  unsigned r = (u + 0x7fffu + ((u >> 16) & 1u)) >> 16;
  return (ushort)r;
}
__device__ __forceinline__ float b2f(ushort u) {
  union { unsigned u; float f; } v; v.u = ((unsigned)u) << 16; return v.f;
}
__device__ __forceinline__ void loadbf4(const ushort* __restrict__ p, float* o) {
  uint2 q = *(const uint2*)p;
  o[0] = b2f((ushort)(q.x & 0xffffu));
  o[1] = b2f((ushort)(q.x >> 16));
  o[2] = b2f((ushort)(q.y & 0xffffu));
  o[3] = b2f((ushort)(q.y >> 16));
}
__device__ __forceinline__ uint2 packbf4(const float* v) {
  uint2 q;
  q.x = (unsigned)f2b(v[0]) | ((unsigned)f2b(v[1]) << 16);
  q.y = (unsigned)f2b(v[2]) | ((unsigned)f2b(v[3]) << 16);
  return q;
}

// ---------- convert fp32 -> bf16 (x and h in one launch) ----------
__global__ __launch_bounds__(256)
void f2b2_kernel(const float* __restrict__ a, const float* __restrict__ b,
                 ushort* __restrict__ oa, ushort* __restrict__ ob) {
  int bid = blockIdx.x;
  const float* in = (bid < 4096) ? a : b;
  ushort* out     = (bid < 4096) ? oa : ob;
  int t = (bid & 4095) * 256 + threadIdx.x;
  float4 v = *(const float4*)(in + (size_t)t * 4);
  float q[4] = {v.x, v.y, v.z, v.w};
  *(uint2*)(out + (size_t)t * 4) = packbf4(q);
}

// ---------- build transposed bf16 weights: Wt[ksel*256+d][h] = W[ksel][h][d] ----------
__global__ __launch_bounds__(256)
void wt2_kernel(const float* __restrict__ L, const float* __restrict__ R,
                ushort* __restrict__ Lt, ushort* __restrict__ Rt) {
  int bid = blockIdx.x;
  const float* W = (bid < 1024) ? L : R;
  ushort* Wt     = (bid < 1024) ? Lt : Rt;
  int idx = (bid & 1023) * 256 + threadIdx.x;
  int c = idx >> 8, hh = idx & 255;
  int ks = c >> 8, d = c & 255;
  Wt[idx] = f2b(W[ks * 65536 + hh * 256 + d]);
}

// ---------- batched GEMM: P[M,N] = A[M,256] @ Wt  (up to 3 jobs per launch) ----------
// 128x128 tile, BK=32 (8 steps), double-buffered stage-early 2-phase, 32 KB LDS
// => 4 blocks/CU (launch_bounds(256,4)), global_load_lds(16B), XOR granule swizzle
// (granule = quad ^ ((row>>1)&3), 2-way bank aliasing = free), XCD-bijective swizzle.
struct GJob {
  const ushort* A; const ushort* B; ushort* out;
  int nx;        // 8 (N=1024) or 4 (N=512)
  int nblocks;   // 128 * nx
};

__global__ __launch_bounds__(256, 4)
void gemm3_kernel(GJob j0, GJob j1, GJob j2, int o1, int o2) {
  __shared__ __align__(16) ushort As[2][128 * 32];   // 2 x 8 KB
  __shared__ __align__(16) ushort Bs[2][128 * 32];   // 2 x 8 KB

  const int bid = blockIdx.x;
  GJob j; int lbid;
  if (bid < o1)      { j = j0; lbid = bid; }
  else if (bid < o2) { j = j1; lbid = bid - o1; }
  else               { j = j2; lbid = bid - o2; }

  const int tid  = threadIdx.x;
  const int lane = tid & 63;
  const int wave = tid >> 6;

  // XCD-bijective block swizzle (nblocks % 8 == 0 and job offsets % 8 == 0)
  const int qq  = j.nblocks >> 3;
  const int id2 = (lbid & 7) * qq + (lbid >> 3);
  int cn, cm;
  if (j.nx == 8) { cn = id2 & 7; cm = id2 >> 3; }
  else           { cn = id2 & 3; cm = id2 >> 2; }
  const int bm = cm * 128;
  const int bn = cn * 128;

  const int wm   = (wave >> 1) * 64;
  const int wn   = (wave & 1) * 64;
  const int row  = lane & 15;
  const int quad = lane >> 4;
  const int gq   = (quad ^ ((row >> 1) & 3)) << 3;   // swizzled read granule (bf16 elems)

  // staging geometry: per step per matrix = 128 rows x 32 bf16 = 8 KB = 8 chunks of 1 KB
  // (16 rows); wave w stages chunks 2w, 2w+1. lane: row-in-chunk = lane>>2, dest granule
  // slot = lane&3, source granule = slot ^ ((lane>>3)&3)  [= (absrow>>1)&3 involution]
  const int l4   = lane >> 2;
  const int gsrc = (lane & 3) ^ ((lane >> 3) & 3);

  f32x4 acc[4][4] = {};

  auto stage = [&](int buf, int kt) {
    const int k0 = kt * 32;
    for (int i = 0; i < 2; ++i) {
      const int ci = wave * 2 + i;
      const int r  = ci * 16 + l4;
      __builtin_amdgcn_global_load_lds(
          (const __attribute__((address_space(1))) void*)(j.A + (size_t)(bm + r) * 256 + k0 + gsrc * 8),
          (__attribute__((address_space(3))) void*)&As[buf][ci * 512], 16, 0, 0);
      __builtin_amdgcn_global_load_lds(
          (const __attribute__((address_space(1))) void*)(j.B + (size_t)(bn + r) * 256 + k0 + gsrc * 8),
          (__attribute__((address_space(3))) void*)&Bs[buf][ci * 512], 16, 0, 0);
    }
  };

  auto compute = [&](int buf) {
    bf16x8 af[4], bf[4];
    for (int f = 0; f < 4; ++f) {
      const int ar = wm + f * 16 + row;
      af[f] = *(const bf16x8*)&As[buf][ar * 32 + gq];
      const int br = wn + f * 16 + row;
      bf[f] = *(const bf16x8*)&Bs[buf][br * 32 + gq];
    }
    __builtin_amdgcn_s_setprio(1);
    for (int ti = 0; ti < 4; ++ti)
      for (int tj = 0; tj < 4; ++tj)
        acc[ti][tj] = __builtin_amdgcn_mfma_f32_16x16x32_bf16(af[ti], bf[tj], acc[ti][tj], 0, 0, 0);
    __builtin_amdgcn_s_setprio(0);
  };

  stage(0, 0);
  __syncthreads();                       // buf0 landed (compiler drains vmcnt before barrier)
#pragma unroll
  for (int t = 0; t < 8; ++t) {
    if (t < 7) stage((t + 1) & 1, t + 1);      // issue next-tile loads BEFORE compute
    __builtin_amdgcn_sched_barrier(0);         // pin the issue ahead of the MFMA cluster
    compute(t & 1);
    if (t < 7) __syncthreads();                // stage(t+1) landed; buf(t) reads done by all waves
  }

  const int N = j.nx * 128;
  for (int ti = 0; ti < 4; ++ti)
    for (int tj = 0; tj < 4; ++tj)
      for (int r2 = 0; r2 < 4; ++r2) {
        const int gm = bm + wm + ti * 16 + quad * 4 + r2;
        const int gn = bn + wn + tj * 16 + row;
        j.out[(size_t)gm * N + gn] = f2b(acc[ti][tj][r2]);
      }
}

// ---------- sigmoid stage: z1 = sig(xL0+hR0+b0) -> slots 0,2 ; r = sig(xL1+hR1+b1) -> slot 1 ----------
__global__ __launch_bounds__(256)
void sig_kernel(const ushort* __restrict__ P0, const ushort* __restrict__ P2,
                const float* __restrict__ bias, float* __restrict__ gnode,
                ushort* __restrict__ z1b, ushort* __restrict__ rb) {
  int t = blockIdx.x * 256 + threadIdx.x;     // 1,048,576
  int b = t >> 6;
  int d0 = (t & 63) * 4;
  float xl[4], hr[4], z[4], r[4];
  // z1
  loadbf4(P0 + (size_t)b * 1024 + d0, xl);
  loadbf4(P2 + (size_t)b * 512 + d0, hr);
  float4 bb = *(const float4*)(bias + d0);
  float bbb[4] = {bb.x, bb.y, bb.z, bb.w};
  for (int i = 0; i < 4; ++i) z[i] = 1.0f / (1.0f + expf(-(xl[i] + hr[i] + bbb[i])));
  size_t g = (size_t)b * 2304 + d0;
  for (int i = 0; i < 4; ++i) { gnode[g + i] = z[i]; gnode[g + 512 + i] = z[i]; }
  *(uint2*)(z1b + (size_t)b * 256 + d0) = packbf4(z);
  // r
  loadbf4(P0 + (size_t)b * 1024 + 256 + d0, xl);
  loadbf4(P2 + (size_t)b * 512 + 256 + d0, hr);
  float4 b1 = *(const float4*)(bias + 256 + d0);
  float b1b[4] = {b1.x, b1.y, b1.z, b1.w};
  for (int i = 0; i < 4; ++i) r[i] = 1.0f / (1.0f + expf(-(xl[i] + hr[i] + b1b[i])));
  for (int i = 0; i < 4; ++i) gnode[g + 256 + i] = r[i];
  *(uint2*)(rb + (size_t)b * 256 + d0) = packbf4(r);
}

// ---------- mixture: cand = f(P1,P2)+b ; softmax over k ; out ; score partials ----------
// mode 0: P1+P2+b   mode 1: 1-(P1+b)   mode 2: P1*P2+b
struct MixJob {
  const ushort* P1; const ushort* P2;
  float* gnode; ushort* act; float* hnext; float* part;
  int mode;
};

__global__ __launch_bounds__(256)
void mixN_kernel(MixJob j0, MixJob j1, MixJob j2, const float* __restrict__ bias,
                 const float* __restrict__ Ws) {
  const int jb = blockIdx.x >> 12;
  const MixJob j = (jb == 0) ? j0 : (jb == 1) ? j1 : j2;
  const int lb = blockIdx.x & 4095;

  const int tid  = threadIdx.x;
  const int wave = tid >> 6;
  const int lane = tid & 63;
  const int row  = lb * 4 + wave;
  const int d0   = lane * 4;
  float c[4][4];
  float sp[4];
  float4 w4 = *(const float4*)(Ws + d0);
  float ws4[4] = {w4.x, w4.y, w4.z, w4.w};
  for (int k = 0; k < 4; ++k) {
    float p1[4];
    loadbf4(j.P1 + (size_t)row * 1024 + k * 256 + d0, p1);
    float4 bb = *(const float4*)(bias + k * 256 + d0);
    float bv[4] = {bb.x, bb.y, bb.z, bb.w};
    float v[4];
    if (j.mode == 0) {
      float p2[4];
      loadbf4(j.P2 + (size_t)row * 1024 + k * 256 + d0, p2);
      for (int i = 0; i < 4; ++i) v[i] = p1[i] + p2[i] + bv[i];
    } else if (j.mode == 1) {
      for (int i = 0; i < 4; ++i) v[i] = 1.0f - (p1[i] + bv[i]);
    } else {
      float p2[4];
      loadbf4(j.P2 + (size_t)row * 1024 + k * 256 + d0, p2);
      for (int i = 0; i < 4; ++i) v[i] = p1[i] * p2[i] + bv[i];
    }
    float s = 0.f;
    for (int i = 0; i < 4; ++i) { c[k][i] = v[i]; s += v[i] * ws4[i]; }
    sp[k] = s;
  }
  for (int m = 1; m < 64; m <<= 1)
    for (int k = 0; k < 4; ++k) sp[k] += __shfl_xor(sp[k], m, 64);
  float mx = fmaxf(fmaxf(sp[0], sp[1]), fmaxf(sp[2], sp[3]));
  float e0 = expf(sp[0] - mx), e1 = expf(sp[1] - mx), e2 = expf(sp[2] - mx), e3 = expf(sp[3] - mx);
  float inv = 1.0f / (e0 + e1 + e2 + e3);
  float w0 = e0 * inv, w1 = e1 * inv, w2 = e2 * inv, w3 = e3 * inv;
  float o[4];
  for (int i = 0; i < 4; ++i) o[i] = w0 * c[0][i] + w1 * c[1][i] + w2 * c[2][i] + w3 * c[3][i];
  size_t g = (size_t)row * 2304 + d0;
  for (int i = 0; i < 4; ++i) j.gnode[g + i] = o[i];
  if (j.act) *(uint2*)(j.act + (size_t)row * 256 + d0) = packbf4(o);
  if (j.hnext) { float4 ov = {o[0], o[1], o[2], o[3]}; *(float4*)(j.hnext + (size_t)row * 256 + d0) = ov; }
  __shared__ float sred[4][4];
  if (lane == 0) for (int k = 0; k < 4; ++k) sred[wave][k] = sp[k];
  __syncthreads();
  if (tid < 4)
    j.part[lb * 4 + tid] = sred[0][tid] + sred[1][tid] + sred[2][tid] + sred[3][tid];
}

// ---------- finalize: reduce score partials, argmax + margin, G_structure ----------
__global__ __launch_bounds__(256)
void fin_kernel(const float* __restrict__ part, float* __restrict__ gs,
                float* __restrict__ margins) {
  __shared__ float red[256][4];
  __shared__ float sfin[6][4];
  int tid = threadIdx.x;
  for (int si = 0; si < 6; ++si) {
    float a[4] = {0.f, 0.f, 0.f, 0.f};
    for (int i = 0; i < 16; ++i) {
      const float* p = part + ((size_t)si * 4096 + tid + 256 * i) * 4;
      for (int k = 0; k < 4; ++k) a[k] += p[k];
    }
    for (int k = 0; k < 4; ++k) red[tid][k] = a[k];
    __syncthreads();
    for (int st = 128; st >= 1; st >>= 1) {
      if (tid < st) for (int k = 0; k < 4; ++k) red[tid][k] += red[tid + st][k];
      __syncthreads();
    }
    if (tid == 0) for (int k = 0; k < 4; ++k) sfin[si][k] = red[0][k];
    __syncthreads();
  }
  if (tid == 0) {
    gs[0] = 0.f; gs[1] = 1.f; gs[2] = 0.f;
    for (int si = 0; si < 6; ++si) {
      float s[4] = {sfin[si][0], sfin[si][1], sfin[si][2], sfin[si][3]};
      int idx = 0; float best = s[0];
      for (int k = 1; k < 4; ++k) if (s[k] > best) { best = s[k]; idx = k; }
      float second = -3.4e38f;
      for (int k = 0; k < 4; ++k) if (k != idx) second = fmaxf(second, s[k]);
      gs[3 + si] = (float)idx;
      margins[si] = best - second;
    }
  }
}

extern "C" void kernel_launch(void* const* d_in, const int* in_sizes, int n_in,
                              void* d_out, int out_size, void* d_ws, size_t ws_size,
                              hipStream_t stream) {
  const float* x    = (const float*)d_in[0];
  const float* h    = (const float*)d_in[1];
  const float* L    = (const float*)d_in[2];
  const float* R    = (const float*)d_in[3];
  const float* bias = (const float*)d_in[4];
  const float* Ws   = (const float*)d_in[5];

  float* out        = (float*)d_out;
  float* out_hnext  = out;                          // 4,194,304
  float* out_gs     = out + 4194304;                // 9
  float* out_gnode  = out + 4194313;                // 16384*9*256
  float* out_marg   = out + 41943049;               // 6

  // workspace layout (bf16 as ushort): 4 P-buffers + activations
  ushort* P0   = (ushort*)d_ws;                     // B*1024 each
  ushort* P1   = P0 + (size_t)BATCH * 1024;
  ushort* P2   = P1 + (size_t)BATCH * 1024;
  ushort* P3   = P2 + (size_t)BATCH * 1024;
  ushort* x2b  = P3 + (size_t)BATCH * 1024;
  ushort* h2b  = x2b + (size_t)BATCH * HID;
  ushort* z1b  = h2b + (size_t)BATCH * HID;
  ushort* rb   = z1b + (size_t)BATCH * HID;
  ushort* rhb  = rb  + (size_t)BATCH * HID;
  ushort* htb  = rhb + (size_t)BATCH * HID;
  ushort* omzb = htb + (size_t)BATCH * HID;
  ushort* ztb  = omzb + (size_t)BATCH * HID;
  ushort* z2hb = ztb + (size_t)BATCH * HID;
  ushort* Lt   = z2hb + (size_t)BATCH * HID;        // 1024*256
  ushort* Rt   = Lt + 1024 * 256;
  float*  part = (float*)(Rt + 1024 * 256);         // 6*16384 floats

  f2b2_kernel<<<8192, 256, 0, stream>>>(x, h, x2b, h2b);
  wt2_kernel<<<2048, 256, 0, stream>>>(L, R, Lt, Rt);

  GJob jz = {};

  // G1: xL->P0 ; hL->P1 ; hR->P2 (N=512)
  {
    GJob a = {x2b, Lt, P0, 8, 1024};
    GJob b = {h2b, Lt, P1, 8, 1024};
    GJob c = {h2b, Rt, P2, 4, 512};
    gemm3_kernel<<<2560, 256, 0, stream>>>(a, b, c, 1024, 2048);
  }
  // sig: z1,r,z2 from xL(P0 slots 0,1) + hR(P2)
  sig_kernel<<<4096, 256, 0, stream>>>(P0, P2, bias, out_gnode, z1b, rb);
  // G2: rR->P2 ; z1R->P3
  {
    GJob a = {rb,  Rt, P2, 8, 1024};
    GJob b = {z1b, Rt, P3, 8, 1024};
    gemm3_kernel<<<2048, 256, 0, stream>>>(a, b, jz, 1024, 2048);
  }
  // M1: rh = sm(hL+rR+b) ; omz = sm(1-(z1R+b)) ; z2h = sm(hL*z1R+b)
  {
    MixJob m0 = {P1, P2, out_gnode + 3 * 256, rhb,  nullptr, part + 0 * 16384, 0};
    MixJob m1 = {P3, P3, out_gnode + 5 * 256, omzb, nullptr, part + 2 * 16384, 1};
    MixJob m2 = {P1, P3, out_gnode + 7 * 256, z2hb, nullptr, part + 4 * 16384, 2};
    mixN_kernel<<<12288, 256, 0, stream>>>(m0, m1, m2, bias, Ws);
  }
  // G3: rhR->P2 ; omzR->P3 ; z2hR->P1
  {
    GJob a = {rhb,  Rt, P2, 8, 1024};
    GJob b = {omzb, Rt, P3, 8, 1024};
    GJob c = {z2hb, Rt, P1, 8, 1024};
    gemm3_kernel<<<3072, 256, 0, stream>>>(a, b, c, 1024, 2048);
  }
  // M2: ht = sm(xL + rhR + b)
  {
    MixJob m0 = {P0, P2, out_gnode + 4 * 256, htb, nullptr, part + 1 * 16384, 0};
    mixN_kernel<<<4096, 256, 0, stream>>>(m0, m0, m0, bias, Ws);
  }
  // G4: htL->P0 (xL dead)
  {
    GJob a = {htb, Lt, P0, 8, 1024};
    gemm3_kernel<<<1024, 256, 0, stream>>>(a, jz, jz, 1024, 1024);
  }
  // M3: zt = sm(htL * omzR + b)
  {
    MixJob m0 = {P0, P3, out_gnode + 6 * 256, ztb, nullptr, part + 3 * 16384, 2};
    mixN_kernel<<<4096, 256, 0, stream>>>(m0, m0, m0, bias, Ws);
  }
  // G5: ztL->P2 (rhR dead)
  {
    GJob a = {ztb, Lt, P2, 8, 1024};
    gemm3_kernel<<<1024, 256, 0, stream>>>(a, jz, jz, 1024, 1024);
  }
  // M4: hn = sm(ztL + z2hR + b) -> gnode8 + hnext(f32)
  {
    MixJob m0 = {P2, P1, out_gnode + 8 * 256, nullptr, out_hnext, part + 5 * 16384, 0};
    mixN_kernel<<<4096, 256, 0, stream>>>(m0, m0, m0, bias, Ws);
  }
  fin_kernel<<<1, 256, 0, stream>>>(part, out_gs, out_marg);
}

// Round 7
// 449.359 us; speedup vs baseline: 1.7988x; 1.0156x over previous
//
#include <hip/hip_runtime.h>

typedef __bf16 bf16_t;
typedef bf16_t bf16x8 __attribute__((ext_vector_type(8)));
typedef float f32x4 __attribute__((ext_vector_type(4)));

#define BATCH 16384
#define HID 256

// ---------- bf16 helpers (manual RNE, no header dependency) ----------
__device__ __forceinline__ ushort f2b(float f) {
  union { float f; unsigned u; } v; v.f = f;
  unsigned u = v.u;
  unsigned r = (u + 0x7fffu + ((u >> 16) & 1u)) >> 16;
  return (ushort)r;
}
__device__ __forceinline__ float b2f(ushort u) {
  union { unsigned u; float f; } v; v.u = ((unsigned)u) << 16; return v.f;
}
__device__ __forceinline__ void loadbf4(const ushort* __restrict__ p, float* o) {
  uint2 q = *(const uint2*)p;
  o[0] = b2f((ushort)(q.x & 0xffffu));
  o[1] = b2f((ushort)(q.x >> 16));
  o[2] = b2f((ushort)(q.y & 0xffffu));
  o[3] = b2f((ushort)(q.y >> 16));
}
__device__ __forceinline__ uint2 packbf4(const float* v) {
  uint2 q;
  q.x = (unsigned)f2b(v[0]) | ((unsigned)f2b(v[1]) << 16);
  q.y = (unsigned)f2b(v[2]) | ((unsigned)f2b(v[3]) << 16);
  return q;
}

// ---------- convert fp32 -> bf16 (x and h in one launch) ----------
__global__ __launch_bounds__(256)
void f2b2_kernel(const float* __restrict__ a, const float* __restrict__ b,
                 ushort* __restrict__ oa, ushort* __restrict__ ob) {
  int bid = blockIdx.x;
  const float* in = (bid < 4096) ? a : b;
  ushort* out     = (bid < 4096) ? oa : ob;
  int t = (bid & 4095) * 256 + threadIdx.x;
  float4 v = *(const float4*)(in + (size_t)t * 4);
  float q[4] = {v.x, v.y, v.z, v.w};
  *(uint2*)(out + (size_t)t * 4) = packbf4(q);
}

// ---------- build transposed bf16 weights: Wt[ksel*256+d][h] = W[ksel][h][d] ----------
__global__ __launch_bounds__(256)
void wt2_kernel(const float* __restrict__ L, const float* __restrict__ R,
                ushort* __restrict__ Lt, ushort* __restrict__ Rt) {
  int bid = blockIdx.x;
  const float* W = (bid < 1024) ? L : R;
  ushort* Wt     = (bid < 1024) ? Lt : Rt;
  int idx = (bid & 1023) * 256 + threadIdx.x;
  int c = idx >> 8, hh = idx & 255;
  int ks = c >> 8, d = c & 255;
  Wt[idx] = f2b(W[ks * 65536 + hh * 256 + d]);
}

// ---------- batched GEMM: P[M,N] = A[M,256] @ Wt  (up to 3 jobs per launch) ----------
// 128x128 tile, BK=32 (8 steps), double-buffered stage-early 2-phase, 32 KB LDS
// => 4 blocks/CU, global_load_lds(16B), XOR granule swizzle, XCD-bijective swizzle.
// Epilogue: per-wave LDS repack (reuses As/Bs) -> coalesced global_store_dwordx4.
struct GJob {
  const ushort* A; const ushort* B; ushort* out;
  int nx;        // 8 (N=1024) or 4 (N=512)
  int nblocks;   // 128 * nx
};

__global__ __launch_bounds__(256, 4)
void gemm3_kernel(GJob j0, GJob j1, GJob j2, int o1, int o2) {
  // flat 32 KB LDS: As[buf] = SH + buf*4096 ; Bs[buf] = SH + 8192 + buf*4096
  // epilogue reuse: wave w C-stage region = SH + w*4096 (64x64 ushort, XOR-swizzled)
  __shared__ __align__(16) ushort SH[16384];

  const int bid = blockIdx.x;
  GJob j; int lbid;
  if (bid < o1)      { j = j0; lbid = bid; }
  else if (bid < o2) { j = j1; lbid = bid - o1; }
  else               { j = j2; lbid = bid - o2; }

  const int tid  = threadIdx.x;
  const int lane = tid & 63;
  const int wave = tid >> 6;

  // XCD-bijective block swizzle (nblocks % 8 == 0 and job offsets % 8 == 0)
  const int qq  = j.nblocks >> 3;
  const int id2 = (lbid & 7) * qq + (lbid >> 3);
  int cn, cm;
  if (j.nx == 8) { cn = id2 & 7; cm = id2 >> 3; }
  else           { cn = id2 & 3; cm = id2 >> 2; }
  const int bm = cm * 128;
  const int bn = cn * 128;

  const int wm   = (wave >> 1) * 64;
  const int wn   = (wave & 1) * 64;
  const int row  = lane & 15;
  const int quad = lane >> 4;
  const int gq   = (quad ^ ((row >> 1) & 3)) << 3;   // swizzled read granule (bf16 elems)

  // staging geometry: per step per matrix = 128 rows x 32 bf16 = 8 KB = 8 chunks of 1 KB
  // (16 rows); wave w stages chunks 2w, 2w+1. lane: row-in-chunk = lane>>2, dest granule
  // slot = lane&3, source granule = slot ^ ((lane>>3)&3)  [= (absrow>>1)&3 involution]
  const int l4   = lane >> 2;
  const int gsrc = (lane & 3) ^ ((lane >> 3) & 3);

  f32x4 acc[4][4] = {};

  auto stage = [&](int buf, int kt) {
    const int k0 = kt * 32;
    for (int i = 0; i < 2; ++i) {
      const int ci = wave * 2 + i;
      const int r  = ci * 16 + l4;
      __builtin_amdgcn_global_load_lds(
          (const __attribute__((address_space(1))) void*)(j.A + (size_t)(bm + r) * 256 + k0 + gsrc * 8),
          (__attribute__((address_space(3))) void*)&SH[buf * 4096 + ci * 512], 16, 0, 0);
      __builtin_amdgcn_global_load_lds(
          (const __attribute__((address_space(1))) void*)(j.B + (size_t)(bn + r) * 256 + k0 + gsrc * 8),
          (__attribute__((address_space(3))) void*)&SH[8192 + buf * 4096 + ci * 512], 16, 0, 0);
    }
  };

  auto compute = [&](int buf) {
    bf16x8 af[4], bf[4];
    for (int f = 0; f < 4; ++f) {
      const int ar = wm + f * 16 + row;
      af[f] = *(const bf16x8*)&SH[buf * 4096 + ar * 32 + gq];
      const int br = wn + f * 16 + row;
      bf[f] = *(const bf16x8*)&SH[8192 + buf * 4096 + br * 32 + gq];
    }
    __builtin_amdgcn_s_setprio(1);
    for (int ti = 0; ti < 4; ++ti)
      for (int tj = 0; tj < 4; ++tj)
        acc[ti][tj] = __builtin_amdgcn_mfma_f32_16x16x32_bf16(af[ti], bf[tj], acc[ti][tj], 0, 0, 0);
    __builtin_amdgcn_s_setprio(0);
  };

  stage(0, 0);
  __syncthreads();                       // buf0 landed (compiler drains vmcnt before barrier)
#pragma unroll
  for (int t = 0; t < 8; ++t) {
    if (t < 7) stage((t + 1) & 1, t + 1);      // issue next-tile loads BEFORE compute
    __builtin_amdgcn_sched_barrier(0);         // pin the issue ahead of the MFMA cluster
    compute(t & 1);
    if (t < 7) __syncthreads();                // stage(t+1) landed; buf(t) reads done by all waves
  }

  // ---- epilogue: LDS repack (wave-private 8 KB quadrant) -> coalesced 16B stores ----
  __syncthreads();                       // all waves done reading As/Bs; safe to reuse
  const int N = j.nx * 128;
  ushort* cw = &SH[wave * 4096];         // [64 rows][8 granules of 8 ushorts], XOR-swizzled
  for (int ti = 0; ti < 4; ++ti)
    for (int tj = 0; tj < 4; ++tj)
      for (int r2 = 0; r2 < 4; ++r2) {
        const int r = ti * 16 + quad * 4 + r2;       // wave-local row 0..63
        const int c = tj * 16 + row;                 // wave-local col 0..63
        cw[r * 64 + ((((c >> 3) ^ (r & 7)) << 3) | (c & 7))] = f2b(acc[ti][tj][r2]);
      }
  // wave-private region + in-order DS pipe: no barrier needed before read-back
  for (int it = 0; it < 8; ++it) {
    const int lr = it * 8 + (lane >> 3);             // wave-local row
    const int ch = lane & 7;                          // 8-col chunk
    const int gp = ch ^ (lr & 7);                     // un-swizzle
    uint4 v = *(const uint4*)&cw[lr * 64 + gp * 8];
    *(uint4*)(j.out + (size_t)(bm + wm + lr) * N + bn + wn + ch * 8) = v;
  }
}

// ---------- sigmoid stage: z1 = sig(xL0+hR0+b0) -> slots 0,2 ; r = sig(xL1+hR1+b1) -> slot 1 ----------
__global__ __launch_bounds__(256)
void sig_kernel(const ushort* __restrict__ P0, const ushort* __restrict__ P2,
                const float* __restrict__ bias, float* __restrict__ gnode,
                ushort* __restrict__ z1b, ushort* __restrict__ rb) {
  int t = blockIdx.x * 256 + threadIdx.x;     // 1,048,576
  int b = t >> 6;
  int d0 = (t & 63) * 4;
  float xl[4], hr[4], z[4], r[4];
  // z1
  loadbf4(P0 + (size_t)b * 1024 + d0, xl);
  loadbf4(P2 + (size_t)b * 512 + d0, hr);
  float4 bb = *(const float4*)(bias + d0);
  float bbb[4] = {bb.x, bb.y, bb.z, bb.w};
  for (int i = 0; i < 4; ++i) z[i] = 1.0f / (1.0f + expf(-(xl[i] + hr[i] + bbb[i])));
  size_t g = (size_t)b * 2304 + d0;
  float4 zv = {z[0], z[1], z[2], z[3]};
  *(float4*)(gnode + g) = zv;             // slot 0
  *(float4*)(gnode + g + 512) = zv;       // slot 2
  *(uint2*)(z1b + (size_t)b * 256 + d0) = packbf4(z);
  // r
  loadbf4(P0 + (size_t)b * 1024 + 256 + d0, xl);
  loadbf4(P2 + (size_t)b * 512 + 256 + d0, hr);
  float4 b1 = *(const float4*)(bias + 256 + d0);
  float b1b[4] = {b1.x, b1.y, b1.z, b1.w};
  for (int i = 0; i < 4; ++i) r[i] = 1.0f / (1.0f + expf(-(xl[i] + hr[i] + b1b[i])));
  float4 rv = {r[0], r[1], r[2], r[3]};
  *(float4*)(gnode + g + 256) = rv;       // slot 1
  *(uint2*)(rb + (size_t)b * 256 + d0) = packbf4(r);
}

// ---------- mixture: cand = f(P1,P2)+b ; softmax over k ; out ; score partials ----------
// mode 0: P1+P2+b   mode 1: 1-(P1+b)   mode 2: P1*P2+b
struct MixJob {
  const ushort* P1; const ushort* P2;
  float* gnode; ushort* act; float* hnext; float* part;
  int mode;
};

__global__ __launch_bounds__(256)
void mixN_kernel(MixJob j0, MixJob j1, MixJob j2, const float* __restrict__ bias,
                 const float* __restrict__ Ws) {
  const int jb = blockIdx.x >> 12;
  const MixJob j = (jb == 0) ? j0 : (jb == 1) ? j1 : j2;
  const int lb = blockIdx.x & 4095;

  const int tid  = threadIdx.x;
  const int wave = tid >> 6;
  const int lane = tid & 63;
  const int row  = lb * 4 + wave;
  const int d0   = lane * 4;
  float c[4][4];
  float sp[4];
  float4 w4 = *(const float4*)(Ws + d0);
  float ws4[4] = {w4.x, w4.y, w4.z, w4.w};
  for (int k = 0; k < 4; ++k) {
    float p1[4];
    loadbf4(j.P1 + (size_t)row * 1024 + k * 256 + d0, p1);
    float4 bb = *(const float4*)(bias + k * 256 + d0);
    float bv[4] = {bb.x, bb.y, bb.z, bb.w};
    float v[4];
    if (j.mode == 0) {
      float p2[4];
      loadbf4(j.P2 + (size_t)row * 1024 + k * 256 + d0, p2);
      for (int i = 0; i < 4; ++i) v[i] = p1[i] + p2[i] + bv[i];
    } else if (j.mode == 1) {
      for (int i = 0; i < 4; ++i) v[i] = 1.0f - (p1[i] + bv[i]);
    } else {
      float p2[4];
      loadbf4(j.P2 + (size_t)row * 1024 + k * 256 + d0, p2);
      for (int i = 0; i < 4; ++i) v[i] = p1[i] * p2[i] + bv[i];
    }
    float s = 0.f;
    for (int i = 0; i < 4; ++i) { c[k][i] = v[i]; s += v[i] * ws4[i]; }
    sp[k] = s;
  }
  for (int m = 1; m < 64; m <<= 1)
    for (int k = 0; k < 4; ++k) sp[k] += __shfl_xor(sp[k], m, 64);
  float mx = fmaxf(fmaxf(sp[0], sp[1]), fmaxf(sp[2], sp[3]));
  float e0 = expf(sp[0] - mx), e1 = expf(sp[1] - mx), e2 = expf(sp[2] - mx), e3 = expf(sp[3] - mx);
  float inv = 1.0f / (e0 + e1 + e2 + e3);
  float w0 = e0 * inv, w1 = e1 * inv, w2 = e2 * inv, w3 = e3 * inv;
  float o[4];
  for (int i = 0; i < 4; ++i) o[i] = w0 * c[0][i] + w1 * c[1][i] + w2 * c[2][i] + w3 * c[3][i];
  size_t g = (size_t)row * 2304 + d0;
  float4 ov = {o[0], o[1], o[2], o[3]};
  *(float4*)(j.gnode + g) = ov;
  if (j.act) *(uint2*)(j.act + (size_t)row * 256 + d0) = packbf4(o);
  if (j.hnext) *(float4*)(j.hnext + (size_t)row * 256 + d0) = ov;
  __shared__ float sred[4][4];
  if (lane == 0) for (int k = 0; k < 4; ++k) sred[wave][k] = sp[k];
  __syncthreads();
  if (tid < 4)
    j.part[lb * 4 + tid] = sred[0][tid] + sred[1][tid] + sred[2][tid] + sred[3][tid];
}

// ---------- finalize: reduce score partials, argmax + margin, G_structure ----------
__global__ __launch_bounds__(256)
void fin_kernel(const float* __restrict__ part, float* __restrict__ gs,
                float* __restrict__ margins) {
  __shared__ float red[256][4];
  __shared__ float sfin[6][4];
  int tid = threadIdx.x;
  for (int si = 0; si < 6; ++si) {
    float a[4] = {0.f, 0.f, 0.f, 0.f};
    for (int i = 0; i < 16; ++i) {
      const float* p = part + ((size_t)si * 4096 + tid + 256 * i) * 4;
      for (int k = 0; k < 4; ++k) a[k] += p[k];
    }
    for (int k = 0; k < 4; ++k) red[tid][k] = a[k];
    __syncthreads();
    for (int st = 128; st >= 1; st >>= 1) {
      if (tid < st) for (int k = 0; k < 4; ++k) red[tid][k] += red[tid + st][k];
      __syncthreads();
    }
    if (tid == 0) for (int k = 0; k < 4; ++k) sfin[si][k] = red[0][k];
    __syncthreads();
  }
  if (tid == 0) {
    gs[0] = 0.f; gs[1] = 1.f; gs[2] = 0.f;
    for (int si = 0; si < 6; ++si) {
      float s[4] = {sfin[si][0], sfin[si][1], sfin[si][2], sfin[si][3]};
      int idx = 0; float best = s[0];
      for (int k = 1; k < 4; ++k) if (s[k] > best) { best = s[k]; idx = k; }
      float second = -3.4e38f;
      for (int k = 0; k < 4; ++k) if (k != idx) second = fmaxf(second, s[k]);
      gs[3 + si] = (float)idx;
      margins[si] = best - second;
    }
  }
}

extern "C" void kernel_launch(void* const* d_in, const int* in_sizes, int n_in,
                              void* d_out, int out_size, void* d_ws, size_t ws_size,
                              hipStream_t stream) {
  const float* x    = (const float*)d_in[0];
  const float* h    = (const float*)d_in[1];
  const float* L    = (const float*)d_in[2];
  const float* R    = (const float*)d_in[3];
  const float* bias = (const float*)d_in[4];
  const float* Ws   = (const float*)d_in[5];

  float* out        = (float*)d_out;
  float* out_hnext  = out;                          // 4,194,304
  float* out_gs     = out + 4194304;                // 9
  float* out_gnode  = out + 4194313;                // 16384*9*256
  float* out_marg   = out + 41943049;               // 6

  // workspace layout (bf16 as ushort): 4 P-buffers + activations
  ushort* P0   = (ushort*)d_ws;                     // B*1024 each
  ushort* P1   = P0 + (size_t)BATCH * 1024;
  ushort* P2   = P1 + (size_t)BATCH * 1024;
  ushort* P3   = P2 + (size_t)BATCH * 1024;
  ushort* x2b  = P3 + (size_t)BATCH * 1024;
  ushort* h2b  = x2b + (size_t)BATCH * HID;
  ushort* z1b  = h2b + (size_t)BATCH * HID;
  ushort* rb   = z1b + (size_t)BATCH * HID;
  ushort* rhb  = rb  + (size_t)BATCH * HID;
  ushort* htb  = rhb + (size_t)BATCH * HID;
  ushort* omzb = htb + (size_t)BATCH * HID;
  ushort* ztb  = omzb + (size_t)BATCH * HID;
  ushort* z2hb = ztb + (size_t)BATCH * HID;
  ushort* Lt   = z2hb + (size_t)BATCH * HID;        // 1024*256
  ushort* Rt   = Lt + 1024 * 256;
  float*  part = (float*)(Rt + 1024 * 256);         // 6*16384 floats

  f2b2_kernel<<<8192, 256, 0, stream>>>(x, h, x2b, h2b);
  wt2_kernel<<<2048, 256, 0, stream>>>(L, R, Lt, Rt);

  GJob jz = {};

  // G1: xL->P0 ; hL->P1 ; hR->P2 (N=512)
  {
    GJob a = {x2b, Lt, P0, 8, 1024};
    GJob b = {h2b, Lt, P1, 8, 1024};
    GJob c = {h2b, Rt, P2, 4, 512};
    gemm3_kernel<<<2560, 256, 0, stream>>>(a, b, c, 1024, 2048);
  }
  // sig: z1,r,z2 from xL(P0 slots 0,1) + hR(P2)
  sig_kernel<<<4096, 256, 0, stream>>>(P0, P2, bias, out_gnode, z1b, rb);
  // G2: rR->P2 ; z1R->P3
  {
    GJob a = {rb,  Rt, P2, 8, 1024};
    GJob b = {z1b, Rt, P3, 8, 1024};
    gemm3_kernel<<<2048, 256, 0, stream>>>(a, b, jz, 1024, 2048);
  }
  // M1: rh = sm(hL+rR+b) ; omz = sm(1-(z1R+b)) ; z2h = sm(hL*z1R+b)
  {
    MixJob m0 = {P1, P2, out_gnode + 3 * 256, rhb,  nullptr, part + 0 * 16384, 0};
    MixJob m1 = {P3, P3, out_gnode + 5 * 256, omzb, nullptr, part + 2 * 16384, 1};
    MixJob m2 = {P1, P3, out_gnode + 7 * 256, z2hb, nullptr, part + 4 * 16384, 2};
    mixN_kernel<<<12288, 256, 0, stream>>>(m0, m1, m2, bias, Ws);
  }
  // G3: rhR->P2 ; omzR->P3 ; z2hR->P1
  {
    GJob a = {rhb,  Rt, P2, 8, 1024};
    GJob b = {omzb, Rt, P3, 8, 1024};
    GJob c = {z2hb, Rt, P1, 8, 1024};
    gemm3_kernel<<<3072, 256, 0, stream>>>(a, b, c, 1024, 2048);
  }
  // M2: ht = sm(xL + rhR + b)
  {
    MixJob m0 = {P0, P2, out_gnode + 4 * 256, htb, nullptr, part + 1 * 16384, 0};
    mixN_kernel<<<4096, 256, 0, stream>>>(m0, m0, m0, bias, Ws);
  }
  // G4: htL->P0 (xL dead)
  {
    GJob a = {htb, Lt, P0, 8, 1024};
    gemm3_kernel<<<1024, 256, 0, stream>>>(a, jz, jz, 1024, 1024);
  }
  // M3: zt = sm(htL * omzR + b)
  {
    MixJob m0 = {P0, P3, out_gnode + 6 * 256, ztb, nullptr, part + 3 * 16384, 2};
    mixN_kernel<<<4096, 256, 0, stream>>>(m0, m0, m0, bias, Ws);
  }
  // G5: ztL->P2 (rhR dead)
  {
    GJob a = {ztb, Lt, P2, 8, 1024};
    gemm3_kernel<<<1024, 256, 0, stream>>>(a, jz, jz, 1024, 1024);
  }
  // M4: hn = sm(ztL + z2hR + b) -> gnode8 + hnext(f32)
  {
    MixJob m0 = {P2, P1, out_gnode + 8 * 256, nullptr, out_hnext, part + 5 * 16384, 0};
    mixN_kernel<<<4096, 256, 0, stream>>>(m0, m0, m0, bias, Ws);
  }
  fin_kernel<<<1, 256, 0, stream>>>(part, out_gs, out_marg);
}